// Round 5
// baseline (7745.501 us; speedup 1.0000x reference)
//
#include <hip/hip_runtime.h>
#include <math.h>

#define H_ 128
#define W_ 128
#define C_ 64
#define O_ 64
#define B_ 8
#define K2_ 9
#define HWSZ (H_*W_)
#define WIN_ 16          // staged window rows (covers |dy| <= 7; cold path beyond)
#define CORD_ 8192       // float offset of coords region in lds

// 8-byte global load with 4-byte alignment guarantee (cold path / phase A).
typedef float f2u __attribute__((ext_vector_type(2), aligned(4)));

// ---------------------------------------------------------------------------
// Kernel P: weight prep (unchanged).
//  wt  (K2, C, O)  : sample-GEMM weights, contiguous in o -> clean s_load.
//  wom (C, 27, 9)  : offset(18)+mask(9) conv weights contiguous per channel.
// ---------------------------------------------------------------------------
__global__ __launch_bounds__(256) void prep_weights_k(
    const float* __restrict__ w, const float* __restrict__ w_off,
    const float* __restrict__ w_mod, float* __restrict__ wt,
    float* __restrict__ wom) {
    int id = blockIdx.x * 256 + threadIdx.x;
    if (id < K2_ * C_ * O_) {              // id = k*C*O + c*O + o
        int o = id & (O_ - 1);
        int c = (id >> 6) & (C_ - 1);
        int k = id / (C_ * O_);
        wt[id] = w[(o * C_ + c) * K2_ + k];
    }
    int id2 = id - K2_ * C_ * O_;
    if (id2 >= 0 && id2 < C_ * 243) {      // id2 = c*243 + t*9 + k
        int k = id2 % 9;
        int tt = (id2 / 9) % 27;
        int c = id2 / 243;
        float v = (tt < 18) ? w_off[(tt * C_ + c) * K2_ + k]
                            : w_mod[((tt - 18) * C_ + c) * K2_ + k];
        wom[id2] = v;
    }
}

// ---------------------------------------------------------------------------
// Fused kernel, round 5.
// Phase A: UNCHANGED from round 4 (one variable at a time); coords go to
//          lds[CORD_ ..] instead of rows 27..53.
// Phase B: LDS-staged channel-pair GEMM. Round-4 lesson: B is bound by
//          distinct-64B-lines through TA (~2.35 cy/line); NCHW re-touches the
//          same geometry 64x (once per channel). Fix: stage [16 rows][128]
//          for a channel PAIR (16 KB, interleaved {chA,chB} float2), double-
//          buffered; taps become ds_read_b64 (even-bank, 2-way = free).
//          Halves split K (k0-3 / k5-8; k4 split by c-chunk half) so both
//          halves share one staging stream; o-reduce at the end as before.
//          Per-k sampling state is precomputed, bit-packed, constant-indexed.
//          |dy|>7 taps (p ~ 1e-8) fall back to global loads (execz-skipped).
// LDS time-slice: A-reduce [0,6912) -> staging [0,8192) + coords [8192,15104)
//          -> o-reduce [0,16384).
// ---------------------------------------------------------------------------
__global__ __launch_bounds__(512, 4) void deform_fused_k(
    const float* __restrict__ x,
    const float* __restrict__ wom, const float* __restrict__ b_off,
    const float* __restrict__ b_mod, const float* __restrict__ wt,
    const float* __restrict__ bias, float* __restrict__ out) {
    __shared__ float lds[O_ * 256];            // 64 KB

    int b     = blockIdx.x & 7;                // batch -> XCD (L2 locality)
    int strip = blockIdx.x >> 3;               // 0..63 : 2-row strip
    int tid   = threadIdx.x;
    int t     = tid & 255;
    int half  = tid >> 8;
    int c0    = __builtin_amdgcn_readfirstlane(half << 5);  // wave-uniform
    int p     = strip * 256 + t;
    int w     = p & (W_ - 1);
    int h     = p >> 7;
    int h0    = strip * 2;

    const float* xb = x + (b * C_ + c0) * HWSZ;   // phase-A c-split base
    const float* xB = x + b * C_ * HWSZ;          // phase-B channel base

    // ======================= phase A: offset/mask conv =====================
    {
        int offs[9];
        float valid[9];
#pragma unroll
        for (int i = 0; i < 9; i++) {
            int dy = i / 3 - 1, dx = i % 3 - 1;
            int yy = h + dy, xx = w + dx;
            bool v = (yy >= 0 && yy < H_ && xx >= 0 && xx < W_);
            int yc = min(max(yy, 0), H_ - 1);
            int xc = min(max(xx, 0), W_ - 1);
            offs[i] = yc * W_ + xc;
            valid[i] = v ? 1.0f : 0.0f;
        }

        float acc27[27];
#pragma unroll
        for (int o = 0; o < 27; o++) acc27[o] = 0.0f;

        float v[9];
#pragma unroll
        for (int i = 0; i < 9; i++) v[i] = xb[offs[i]] * valid[i];

        for (int c = 0; c < 32; c++) {
            const float* xn = xb + min(c + 1, 31) * HWSZ;
            float vn[9];
#pragma unroll
            for (int i = 0; i < 9; i++) vn[i] = xn[offs[i]] * valid[i];

            const float* wc = wom + (c0 + c) * 243;   // uniform -> s_load
#pragma unroll
            for (int o = 0; o < 27; o++) {
#pragma unroll
                for (int kk = 0; kk < 9; kk++) acc27[o] += v[kk] * wc[o * 9 + kk];
            }
#pragma unroll
            for (int i = 0; i < 9; i++) v[i] = vn[i];
        }

        if (half) {
#pragma unroll
            for (int o = 0; o < 27; o++) lds[o * 256 + t] = acc27[o];
        }
        __syncthreads();
        if (!half) {
#pragma unroll
            for (int k = 0; k < 9; k++) {
                float dy = acc27[2 * k]     + lds[(2 * k)     * 256 + t] + b_off[2 * k];
                float dx = acc27[2 * k + 1] + lds[(2 * k + 1) * 256 + t] + b_off[2 * k + 1];
                float mm = acc27[18 + k]    + lds[(18 + k)    * 256 + t] + b_mod[k];
                float mask = 2.0f / (1.0f + __expf(-mm));
                float py = dy + (float)h - 1.0f + (float)(k / 3);
                float px = dx + (float)w - 1.0f + (float)(k % 3);
                lds[CORD_ + (3 * k + 0) * 256 + t] = py;
                lds[CORD_ + (3 * k + 1) * 256 + t] = px;
                lds[CORD_ + (3 * k + 2) * 256 + t] = mask;
            }
        }
        __syncthreads();
    }

    // ======================= phase B: sample + GEMM ========================
    float acc[O_];
#pragma unroll
    for (int o = 0; o < O_; o++) acc[o] = 0.0f;

    int lo = min(max(h0 - 7, 0), H_ - WIN_);   // staged window [lo, lo+16)

    // per-k sampling state (constant-indexed -> registers).
    // half0 owns k=0..3 (+k4 for cp<16); half1 owns k=5..8 (+k4 for cp>=16).
    float ca0[5], ca1[5], ca2[5], ca3[5];
    int   cpk[5], wko[5];
#pragma unroll
    for (int i = 0; i < 5; i++) {
        int k = (half == 0) ? ((i < 4) ? i : 4) : ((i < 4) ? 5 + i : 4);
        float py = lds[CORD_ + (3 * k + 0) * 256 + t];
        float px = lds[CORD_ + (3 * k + 1) * 256 + t];
        float m  = lds[CORD_ + (3 * k + 2) * 256 + t];

        float y0f = floorf(py), x0f = floorf(px);
        float wy = py - y0f, wx = px - x0f;
        int y0 = (int)y0f, x0 = (int)x0f;
        int y1 = y0 + 1;
        float vy0 = (y0 >= 0 && y0 < H_) ? 1.0f : 0.0f;
        float vy1 = (y1 >= 0 && y1 < H_) ? 1.0f : 0.0f;
        float vx0 = (x0 >= 0 && x0 < W_) ? 1.0f : 0.0f;
        float vx1 = (x0 >= -1 && x0 < W_ - 1) ? 1.0f : 0.0f;
        int y0c = min(max(y0, 0), H_ - 1), y1c = min(max(y1, 0), H_ - 1);

        float w00 = (1.0f - wy) * (1.0f - wx) * vy0 * vx0 * m;
        float w01 = (1.0f - wy) * wx * vy0 * vx1 * m;
        float w10 = wy * (1.0f - wx) * vy1 * vx0 * m;
        float w11 = wy * wx * vy1 * vx1 * m;

        // column-pair fold (cols lc, lc+1 always valid & staged)
        int lc   = min(max(x0, 0), W_ - 2);
        bool xlo = (x0 < 0);
        bool xhi = (x0 > W_ - 2);
        ca0[i] = xhi ? 0.0f : (xlo ? w01 : w00);
        ca1[i] = xlo ? 0.0f : (xhi ? w00 : w01);
        ca2[i] = xhi ? 0.0f : (xlo ? w11 : w10);
        ca3[i] = xlo ? 0.0f : (xhi ? w10 : w11);

        int r0c = min(max(y0c - lo, 0), WIN_ - 1);
        int r1c = min(max(y1c - lo, 0), WIN_ - 1);
        int in0 = (y0c >= lo && y0c < lo + WIN_) ? 1 : 0;
        int in1 = (y1c >= lo && y1c < lo + WIN_) ? 1 : 0;
        cpk[i] = lc | (r0c << 7) | (r1c << 11) | (in0 << 15) | (in1 << 16)
               | (y0c << 17) | (y1c << 24);
        wko[i] = k * (C_ * O_);
    }

    // staging geometry: thread covers 4 cols of one row, both channels.
    int srow = tid >> 5;                 // 0..15
    int scol = (tid * 4) & 127;          // multiple of 4 -> float4 aligned

    // stage chunk 0 (channels 0,1) into buffer 0
    {
        const float* sA = xB + (lo + srow) * W_ + scol;
        float4 ga = *(const float4*)sA;
        float4 gb = *(const float4*)(sA + HWSZ);
        float2* d = (float2*)lds + srow * 128 + scol;
        d[0] = make_float2(ga.x, gb.x);
        d[1] = make_float2(ga.y, gb.y);
        d[2] = make_float2(ga.z, gb.z);
        d[3] = make_float2(ga.w, gb.w);
    }
    __syncthreads();

#define DOK(i)                                                                 \
    {                                                                          \
        int pk = cpk[i];                                                       \
        int lc_ = pk & 127;                                                    \
        int i0 = (((pk >> 7) & 15) << 7) + lc_;                                \
        int i1 = (((pk >> 11) & 15) << 7) + lc_;                               \
        float2 p00 = Lb[i0], p01 = Lb[i0 + 1];                                 \
        float2 p10 = Lb[i1], p11 = Lb[i1 + 1];                                 \
        if (__builtin_expect((pk & (1 << 15)) == 0, 0)) {                      \
            const float* xa = xc2 + ((pk >> 17) & 127) * W_ + lc_;             \
            f2u g0 = *(const f2u*)xa;                                          \
            f2u g1 = *(const f2u*)(xa + HWSZ);                                 \
            p00 = make_float2(g0.x, g1.x);                                     \
            p01 = make_float2(g0.y, g1.y);                                     \
        }                                                                      \
        if (__builtin_expect((pk & (1 << 16)) == 0, 0)) {                      \
            const float* xa = xc2 + ((pk >> 24) & 127) * W_ + lc_;             \
            f2u g0 = *(const f2u*)xa;                                          \
            f2u g1 = *(const f2u*)(xa + HWSZ);                                 \
            p10 = make_float2(g0.x, g1.x);                                     \
            p11 = make_float2(g0.y, g1.y);                                     \
        }                                                                      \
        float sA = ca0[i] * p00.x + ca1[i] * p01.x + ca2[i] * p10.x + ca3[i] * p11.x; \
        float sB = ca0[i] * p00.y + ca1[i] * p01.y + ca2[i] * p10.y + ca3[i] * p11.y; \
        const float* wA = wck + wko[i];                                        \
        const float* wB = wA + O_;                                             \
        _Pragma("unroll")                                                      \
        for (int o = 0; o < O_; o++) acc[o] += sA * wA[o] + sB * wB[o];        \
    }

    for (int cp = 0; cp < 32; cp++) {
        // prefetch next chunk's global data (in flight across compute)
        float4 ga, gb;
        if (cp < 31) {
            const float* sA = xB + (2 * (cp + 1)) * HWSZ + (lo + srow) * W_ + scol;
            ga = *(const float4*)sA;
            gb = *(const float4*)(sA + HWSZ);
        }

        const float2* Lb  = (const float2*)(lds + (cp & 1) * 4096);
        const float*  wck = wt + 2 * cp * O_;          // uniform -> s_load
        const float*  xc2 = xB + 2 * cp * HWSZ;        // cold-path base (ch pair)

        DOK(0); DOK(1); DOK(2); DOK(3);
        if ((cp < 16) != (half != 0)) DOK(4);          // k4: half0 cp<16, half1 cp>=16

        __syncthreads();
        if (cp < 31) {
            float2* d = (float2*)(lds + ((cp + 1) & 1) * 4096) + srow * 128 + scol;
            d[0] = make_float2(ga.x, gb.x);
            d[1] = make_float2(ga.y, gb.y);
            d[2] = make_float2(ga.z, gb.z);
            d[3] = make_float2(ga.w, gb.w);
        }
        __syncthreads();
    }
#undef DOK

    // ======================= o-reduce epilogue =============================
    if (half) {
#pragma unroll
        for (int o = 0; o < O_; o++) lds[o * 256 + t] = acc[o];  // stride-1
    }
    __syncthreads();
    if (!half) {
        int obase = b * O_ * HWSZ + p;
#pragma unroll
        for (int o = 0; o < O_; o++)
            out[obase + o * HWSZ] = acc[o] + lds[o * 256 + t] + bias[o];
    }
}

// ---------------------------------------------------------------------------
extern "C" void kernel_launch(void* const* d_in, const int* in_sizes, int n_in,
                              void* d_out, int out_size, void* d_ws, size_t ws_size,
                              hipStream_t stream) {
    const float* x     = (const float*)d_in[0];
    const float* w_off = (const float*)d_in[1];
    const float* b_off = (const float*)d_in[2];
    const float* w_mod = (const float*)d_in[3];
    const float* b_mod = (const float*)d_in[4];
    const float* w     = (const float*)d_in[5];
    const float* bias  = (const float*)d_in[6];
    float* out = (float*)d_out;

    float* wt  = (float*)d_ws;            // 36,864 floats
    float* wom = wt + K2_ * C_ * O_;      // 15,552 floats

    const int nPrep = K2_ * C_ * O_ + C_ * 243;
    hipLaunchKernelGGL(prep_weights_k, dim3((nPrep + 255) / 256), dim3(256),
                       0, stream, w, w_off, w_mod, wt, wom);
    hipLaunchKernelGGL(deform_fused_k, dim3(512), dim3(512), 0, stream,
                       x, wom, b_off, b_mod, wt, bias, out);
}

// Round 6
// 1365.556 us; speedup vs baseline: 5.6720x; 5.6720x over previous
//
#include <hip/hip_runtime.h>
#include <math.h>

#define H_ 128
#define W_ 128
#define C_ 64
#define O_ 64
#define B_ 8
#define K2_ 9
#define HWSZ (H_*W_)
#define WIN_ 16          // staged window rows (covers |dy| <= 7; cold path beyond)
#define AOUT_ 8192       // float offset: A-outs region, 28*256 floats (pass1->coords)
#define SBUF_ 8192       // float offset: s-exchange region, 9*256 float2 (pass2)

// 8-byte global load with 4-byte alignment guarantee (cold path).
typedef float f2u __attribute__((ext_vector_type(2), aligned(4)));

// ---------------------------------------------------------------------------
// Kernel P: weight prep.
//  wt  (K2, C, O)   : sample-GEMM weights, contiguous in o -> clean s_load.
//  wom (C, 28, 9)   : offset(18)+mask(9) conv weights per channel, row 27 = 0
//                     (pad so both output-halves can run a fixed 14-row loop).
// ---------------------------------------------------------------------------
__global__ __launch_bounds__(256) void prep_weights_k(
    const float* __restrict__ w, const float* __restrict__ w_off,
    const float* __restrict__ w_mod, float* __restrict__ wt,
    float* __restrict__ wom) {
    int id = blockIdx.x * 256 + threadIdx.x;
    if (id < K2_ * C_ * O_) {              // id = k*C*O + c*O + o
        int o = id & (O_ - 1);
        int c = (id >> 6) & (C_ - 1);
        int k = id / (C_ * O_);
        wt[id] = w[(o * C_ + c) * K2_ + k];
    }
    int id2 = id - K2_ * C_ * O_;
    if (id2 >= 0 && id2 < C_ * 252) {      // id2 = c*252 + tt*9 + k
        int k = id2 % 9;
        int tt = (id2 / 9) % 28;
        int c = id2 / 252;
        float v = 0.0f;
        if (tt < 18)      v = w_off[(tt * C_ + c) * K2_ + k];
        else if (tt < 27) v = w_mod[((tt - 18) * C_ + c) * K2_ + k];
        wom[id2] = v;
    }
}

// ---------------------------------------------------------------------------
// Fused kernel, round 6.
// Round-5 lesson: held state (acc[64]+30 k-state regs) spilled the
// accumulator to scratch (26.6 GB HBM traffic, VALUBusy 2%). Fix is
// structural register reduction, keeping the LDS-staging concept:
//  - PASS 1 (offset/mask conv): halves split the 27 OUTPUTS (accA[14]);
//    taps come from the staged window (A's 3x3 stencil is always inside),
//    killing old A's dependent-global-gather stalls. No A-reduce.
//  - coords: A-sums exchanged via LDS; each half builds sampling state for
//    its k-group only (5 entries = 25 regs, constant-indexed).
//  - PASS 2 (sample+GEMM): halves split K for sampling (blended scalars s
//    exchanged via a 4.6KB LDS s-buf) and split OUTPUTS for the FMA
//    (acc[32]). out[o] = sum_{k,c} s[k,c] * wt[k,c,o].
// Staging: [16 rows][128 cols] per channel-PAIR, interleaved {chA,chB}
// float2 (taps = ds_read_b64, conflict-free for near-consecutive lanes),
// double-buffered 32KB, float4 global loads, prefetch-ahead one chunk.
// LDS 61.4KB total -> 2 blocks/CU (16 waves). Live regs ~90 < 128 cap.
// ---------------------------------------------------------------------------
__global__ __launch_bounds__(512, 4) void deform_fused_k(
    const float* __restrict__ x,
    const float* __restrict__ wom, const float* __restrict__ b_off,
    const float* __restrict__ b_mod, const float* __restrict__ wt,
    const float* __restrict__ bias, float* __restrict__ out) {
    __shared__ float lds[15360];               // 61,440 B

    int b     = blockIdx.x & 7;                // batch -> XCD (L2 locality)
    int strip = blockIdx.x >> 3;               // 0..63 : 2-row strip
    int tid   = threadIdx.x;
    int t     = tid & 255;
    int half  = tid >> 8;
    int p     = strip * 256 + t;
    int w     = p & (W_ - 1);
    int h     = p >> 7;
    int h0    = strip * 2;
    int lo    = min(max(h0 - 7, 0), H_ - WIN_);   // window rows [lo, lo+16)

    const float* xB = x + b * C_ * HWSZ;

    // staging geometry: thread = (row, 4-col group); float4 in, 4x float2 out.
    int srow  = tid >> 5;                      // 0..15
    int scol  = (tid & 31) * 4;                // 0..124
    int sgoff = (lo + srow) * W_ + scol;       // global offset in channel plane

#define STAGE(CHPAIR, BUF)                                                     \
    {                                                                          \
        const float* s0 = xB + (2 * (CHPAIR)) * HWSZ + sgoff;                  \
        float4 ga = *(const float4*)s0;                                        \
        float4 gb = *(const float4*)(s0 + HWSZ);                               \
        float2* d = (float2*)lds + (BUF) * 2048 + srow * W_ + scol;            \
        d[0] = make_float2(ga.x, gb.x); d[1] = make_float2(ga.y, gb.y);        \
        d[2] = make_float2(ga.z, gb.z); d[3] = make_float2(ga.w, gb.w);        \
    }

    // ===================== pass 1: offset/mask conv ========================
    int aoff[9]; float avalid[9];
#pragma unroll
    for (int i = 0; i < 9; i++) {
        int dy = i / 3 - 1, dx = i % 3 - 1;
        int yy = h + dy, xx = w + dx;
        bool v = (yy >= 0 && yy < H_ && xx >= 0 && xx < W_);
        int yc = min(max(yy, 0), H_ - 1);
        int xc = min(max(xx, 0), W_ - 1);
        aoff[i] = (yc - lo) * W_ + xc;         // always in window (stencil)
        avalid[i] = v ? 1.0f : 0.0f;
    }

    float accA[14];
#pragma unroll
    for (int o = 0; o < 14; o++) accA[o] = 0.0f;
    int o0A9 = half * 14 * 9;                  // wom sub-block for this half

    STAGE(0, 0);
    __syncthreads();

    for (int cp = 0; cp < 32; cp++) {
        float4 ga, gb;
        if (cp < 31) {                         // prefetch next chunk
            const float* sn = xB + (2 * (cp + 1)) * HWSZ + sgoff;
            ga = *(const float4*)sn;
            gb = *(const float4*)(sn + HWSZ);
        }
        const float2* S = (const float2*)lds + (cp & 1) * 2048;
        float vA[9], vB[9];
#pragma unroll
        for (int i = 0; i < 9; i++) {
            float2 tv = S[aoff[i]];
            vA[i] = tv.x * avalid[i];
            vB[i] = tv.y * avalid[i];
        }
        const float* wA = wom + (2 * cp) * 252 + o0A9;   // uniform -> s_load
        const float* wB = wA + 252;
#pragma unroll
        for (int o = 0; o < 14; o++) {
#pragma unroll
            for (int i = 0; i < 9; i++)
                accA[o] += vA[i] * wA[o * 9 + i] + vB[i] * wB[o * 9 + i];
        }
        if (cp < 31) {                         // write next buf (safe: readers
            float2* d = (float2*)lds + ((cp + 1) & 1) * 2048 + srow * W_ + scol;
            d[0] = make_float2(ga.x, gb.x); d[1] = make_float2(ga.y, gb.y);
            d[2] = make_float2(ga.z, gb.z); d[3] = make_float2(ga.w, gb.w);
        }                                      //  of that buf done last barrier)
        __syncthreads();
    }

    // A-sums -> LDS (row 27 is the padded-garbage row, never read)
#pragma unroll
    for (int o = 0; o < 14; o++) lds[AOUT_ + (half * 14 + o) * 256 + t] = accA[o];
    __syncthreads();

    // ============ coords -> per-k sampling state (constant-indexed) ========
    // half0 owns k=0..3 (+k4); half1 owns k=5..8 (k4 state built, sampling
    // of entry 4 done by half0 only -- both channels of each s come from the
    // same half since taps are channel-pair float2 reads).
    float ca0[5], ca1[5], ca2[5], ca3[5];
    int   cpk[5];
    int   kbase = half ? 5 : 0;
#pragma unroll
    for (int i = 0; i < 5; i++) {
        int k = (i < 4) ? (kbase + i) : 4;
        float dy = lds[AOUT_ + (2 * k) * 256 + t]     + b_off[2 * k];
        float dx = lds[AOUT_ + (2 * k + 1) * 256 + t] + b_off[2 * k + 1];
        float mm = lds[AOUT_ + (18 + k) * 256 + t]    + b_mod[k];
        float mask = 2.0f / (1.0f + __expf(-mm));
        float py = dy + (float)h - 1.0f + (float)(k / 3);
        float px = dx + (float)w - 1.0f + (float)(k % 3);

        float y0f = floorf(py), x0f = floorf(px);
        float wy = py - y0f, wx = px - x0f;
        int y0 = (int)y0f, x0 = (int)x0f;
        int y1 = y0 + 1;
        float vy0 = (y0 >= 0 && y0 < H_) ? 1.0f : 0.0f;
        float vy1 = (y1 >= 0 && y1 < H_) ? 1.0f : 0.0f;
        float vx0 = (x0 >= 0 && x0 < W_) ? 1.0f : 0.0f;
        float vx1 = (x0 >= -1 && x0 < W_ - 1) ? 1.0f : 0.0f;
        int y0c = min(max(y0, 0), H_ - 1), y1c = min(max(y1, 0), H_ - 1);

        float w00 = (1.0f - wy) * (1.0f - wx) * vy0 * vx0 * mask;
        float w01 = (1.0f - wy) * wx * vy0 * vx1 * mask;
        float w10 = wy * (1.0f - wx) * vy1 * vx0 * mask;
        float w11 = wy * wx * vy1 * vx1 * mask;

        int lc   = min(max(x0, 0), W_ - 2);    // cols lc, lc+1 staged & valid
        bool xlo = (x0 < 0);
        bool xhi = (x0 > W_ - 2);
        ca0[i] = xhi ? 0.0f : (xlo ? w01 : w00);
        ca1[i] = xlo ? 0.0f : (xhi ? w00 : w01);
        ca2[i] = xhi ? 0.0f : (xlo ? w11 : w10);
        ca3[i] = xlo ? 0.0f : (xhi ? w10 : w11);

        int r0c = min(max(y0c - lo, 0), WIN_ - 1);
        int r1c = min(max(y1c - lo, 0), WIN_ - 1);
        int in0 = (y0c >= lo && y0c < lo + WIN_) ? 1 : 0;
        int in1 = (y1c >= lo && y1c < lo + WIN_) ? 1 : 0;
        cpk[i] = lc | (r0c << 7) | (r1c << 11) | (in0 << 15) | (in1 << 16)
               | (y0c << 17) | (y1c << 24);
    }
    __syncthreads();                           // A-outs dead; SBUF reuse ok

    // ===================== pass 2: sample + GEMM ===========================
    float acc[32];
#pragma unroll
    for (int o = 0; o < 32; o++) acc[o] = 0.0f;
    int o0 = half << 5;
    float2* sb = (float2*)(lds + SBUF_);

    STAGE(0, 0);
    __syncthreads();

    for (int cp = 0; cp < 32; cp++) {
        float4 ga, gb;
        if (cp < 31) {
            const float* sn = xB + (2 * (cp + 1)) * HWSZ + sgoff;
            ga = *(const float4*)sn;
            gb = *(const float4*)(sn + HWSZ);
        }
        const float2* S   = (const float2*)lds + (cp & 1) * 2048;
        const float* xc2  = xB + 2 * cp * HWSZ;     // cold-path base

#pragma unroll
        for (int i = 0; i < 5; i++) {
            if (i == 4 && half) break;         // k4 sampled by half0 only
            int pk = cpk[i];
            int lc = pk & 127;
            int i0 = ((pk >> 7) & 15) * W_ + lc;
            int i1 = ((pk >> 11) & 15) * W_ + lc;
            float2 p00 = S[i0], p01 = S[i0 + 1];
            float2 p10 = S[i1], p11 = S[i1 + 1];
            if (__builtin_expect((pk & (1 << 15)) == 0, 0)) {
                const float* xa = xc2 + ((pk >> 17) & 127) * W_ + lc;
                f2u g0 = *(const f2u*)xa;
                f2u g1 = *(const f2u*)(xa + HWSZ);
                p00 = make_float2(g0.x, g1.x);
                p01 = make_float2(g0.y, g1.y);
            }
            if (__builtin_expect((pk & (1 << 16)) == 0, 0)) {
                const float* xa = xc2 + ((pk >> 24) & 127) * W_ + lc;
                f2u g0 = *(const f2u*)xa;
                f2u g1 = *(const f2u*)(xa + HWSZ);
                p10 = make_float2(g0.x, g1.x);
                p11 = make_float2(g0.y, g1.y);
            }
            float sA = ca0[i] * p00.x + ca1[i] * p01.x + ca2[i] * p10.x + ca3[i] * p11.x;
            float sB = ca0[i] * p00.y + ca1[i] * p01.y + ca2[i] * p10.y + ca3[i] * p11.y;
            int k = (i < 4) ? (kbase + i) : 4;
            sb[k * 256 + t] = make_float2(sA, sB);
        }
        if (cp < 31) {
            float2* d = (float2*)lds + ((cp + 1) & 1) * 2048 + srow * W_ + scol;
            d[0] = make_float2(ga.x, gb.x); d[1] = make_float2(ga.y, gb.y);
            d[2] = make_float2(ga.z, gb.z); d[3] = make_float2(ga.w, gb.w);
        }
        __syncthreads();                       // s + next staging visible

        const float* wk = wt + (2 * cp) * O_ + o0;     // uniform -> s_load
#pragma unroll
        for (int k = 0; k < 9; k++) {
            float2 s = sb[k * 256 + t];
            const float* wA = wk + k * (C_ * O_);
            const float* wB = wA + O_;
#pragma unroll
            for (int o = 0; o < 32; o++) acc[o] += s.x * wA[o] + s.y * wB[o];
        }
        __syncthreads();                       // s-buf consumed before rewrite
    }
#undef STAGE

    // ======================= direct write-out ==============================
    int obase = b * O_ * HWSZ + o0 * HWSZ + p;
#pragma unroll
    for (int o = 0; o < 32; o++)
        out[obase + o * HWSZ] = acc[o] + bias[o0 + o];
}

// ---------------------------------------------------------------------------
extern "C" void kernel_launch(void* const* d_in, const int* in_sizes, int n_in,
                              void* d_out, int out_size, void* d_ws, size_t ws_size,
                              hipStream_t stream) {
    const float* x     = (const float*)d_in[0];
    const float* w_off = (const float*)d_in[1];
    const float* b_off = (const float*)d_in[2];
    const float* w_mod = (const float*)d_in[3];
    const float* b_mod = (const float*)d_in[4];
    const float* w     = (const float*)d_in[5];
    const float* bias  = (const float*)d_in[6];
    float* out = (float*)d_out;

    float* wt  = (float*)d_ws;            // 36,864 floats
    float* wom = wt + K2_ * C_ * O_;      // 16,128 floats (C*28*9)

    const int nPrep = K2_ * C_ * O_ + C_ * 252;   // 52,992
    hipLaunchKernelGGL(prep_weights_k, dim3((nPrep + 255) / 256), dim3(256),
                       0, stream, w, w_off, w_mod, wt, wom);
    hipLaunchKernelGGL(deform_fused_k, dim3(512), dim3(512), 0, stream,
                       x, wom, b_off, b_mod, wt, bias, out);
}

// Round 7
// 484.624 us; speedup vs baseline: 15.9825x; 2.8178x over previous
//
#include <hip/hip_runtime.h>
#include <math.h>

#define H_ 128
#define W_ 128
#define C_ 64
#define O_ 64
#define B_ 8
#define K2_ 9
#define HWSZ (H_*W_)
#define WIN_ 16          // B-kernel staged window rows (|dy|<=7 hot; cold path beyond)

// 8-byte global load with 4-byte alignment guarantee (cold path).
typedef float f2u __attribute__((ext_vector_type(2), aligned(4)));

// ---------------------------------------------------------------------------
// Kernel P: weight prep.
//  wt  (K2, C, O)  : sample-GEMM weights, contiguous in o -> clean s_load.
//  wom (C, 28, 9)  : offset(18)+mask(9) conv weights per channel, row 27 = 0
//                    (pad so 4 output-quarters can run fixed 7-row loops).
// ---------------------------------------------------------------------------
__global__ __launch_bounds__(256) void prep_weights_k(
    const float* __restrict__ w, const float* __restrict__ w_off,
    const float* __restrict__ w_mod, float* __restrict__ wt,
    float* __restrict__ wom) {
    int id = blockIdx.x * 256 + threadIdx.x;
    if (id < K2_ * C_ * O_) {              // id = k*C*O + c*O + o
        int o = id & (O_ - 1);
        int c = (id >> 6) & (C_ - 1);
        int k = id / (C_ * O_);
        wt[id] = w[(o * C_ + c) * K2_ + k];
    }
    int id2 = id - K2_ * C_ * O_;
    if (id2 >= 0 && id2 < C_ * 252) {      // id2 = c*252 + tt*9 + k
        int k = id2 % 9;
        int tt = (id2 / 9) % 28;
        int c = id2 / 252;
        float v = 0.0f;
        if (tt < 18)      v = w_off[(tt * C_ + c) * K2_ + k];
        else if (tt < 27) v = w_mod[((tt - 18) * C_ + c) * K2_ + k];
        wom[id2] = v;
    }
}

// ---------------------------------------------------------------------------
// Kernel A2: offset/mask 3x3 conv with LDS-staged stencil window.
// Block = 512 thr = 128 pixels (1 row) x 4 output-quarters (7 outs each,
// row 27 = zero pad). Channel-PAIR sweep: stage [4 rows][128 cols] {chA,chB}
// float2 (2.5 KB/buf, double-buffered), taps via conflict-free ds_read_b64
// (consecutive lanes -> consecutive float2 = 2-way aliasing = free).
// Weight base readfirstlane'd -> s_load (round-0/6 lesson: divergent-looking
// base turns the weight stream into per-lane vector loads, 17x VMEM).
// Grid 1024 = 8 batches x 128 rows -> 32 waves/CU target.
// ---------------------------------------------------------------------------
__global__ __launch_bounds__(512, 4) void conv_offmask_k(
    const float* __restrict__ x,
    const float* __restrict__ wom, const float* __restrict__ b_off,
    const float* __restrict__ b_mod,
    float* __restrict__ pyA, float* __restrict__ pxA, float* __restrict__ mA) {
    __shared__ float lds[5632];            // [0,2048) staging dbuf; [2048,5632) AOUT

    int b    = blockIdx.x & 7;             // batch -> XCD (L2 locality)
    int hrow = blockIdx.x >> 3;            // 0..127 : pixel row
    int tid  = threadIdx.x;
    int t    = tid & 127;                  // pixel col
    int q    = tid >> 7;                   // 0..3 : output quarter
    int qu   = __builtin_amdgcn_readfirstlane(q);   // SGPR copy for weight base
    int p    = hrow * W_ + t;
    int lo_a = min(max(hrow - 1, 0), H_ - 4);       // staged rows [lo_a, lo_a+4)

    const float* xB = x + b * C_ * HWSZ;

    // stencil taps: always inside the 4-row window
    int aoff[9]; float avalid[9];
#pragma unroll
    for (int i = 0; i < 9; i++) {
        int dy = i / 3 - 1, dx = i % 3 - 1;
        int yy = hrow + dy, xx = t + dx;
        bool v = (yy >= 0 && yy < H_ && xx >= 0 && xx < W_);
        int yc = min(max(yy, 0), H_ - 1);
        int xc = min(max(xx, 0), W_ - 1);
        aoff[i] = (yc - lo_a) * W_ + xc;
        avalid[i] = v ? 1.0f : 0.0f;
    }

    float accA[7];
#pragma unroll
    for (int o = 0; o < 7; o++) accA[o] = 0.0f;

    // staging map: thread -> (row=q, col=t); lanes write consecutive float2
    {
        const float* s0 = xB + (lo_a + q) * W_ + t;
        ((float2*)lds)[q * W_ + t] = make_float2(s0[0], s0[HWSZ]);
    }
    __syncthreads();

    for (int cp = 0; cp < 32; cp++) {
        float pa = 0.0f, pb = 0.0f;
        if (cp < 31) {                     // prefetch next channel-pair
            const float* sn = xB + (2 * (cp + 1)) * HWSZ + (lo_a + q) * W_ + t;
            pa = sn[0]; pb = sn[HWSZ];
        }
        const float2* S = (const float2*)lds + (cp & 1) * 512;
        float vA[9], vB[9];
#pragma unroll
        for (int i = 0; i < 9; i++) {
            float2 tv = S[aoff[i]];
            vA[i] = tv.x * avalid[i];
            vB[i] = tv.y * avalid[i];
        }
        const float* wA = wom + (2 * cp) * 252 + qu * 63;   // SGPR base -> s_load
        const float* wB = wA + 252;
#pragma unroll
        for (int o = 0; o < 7; o++) {
#pragma unroll
            for (int i = 0; i < 9; i++)
                accA[o] += vA[i] * wA[o * 9 + i] + vB[i] * wB[o * 9 + i];
        }
        if (cp < 31)
            ((float2*)lds)[((cp + 1) & 1) * 512 + q * W_ + t] = make_float2(pa, pb);
        __syncthreads();
    }

    // exchange quarter sums, then 3 k's per quarter (q3 idle) -> coords out
    float* AO = lds + 2048;
#pragma unroll
    for (int o = 0; o < 7; o++) AO[(q * 7 + o) * 128 + t] = accA[o];
    __syncthreads();
    if (q < 3) {
#pragma unroll
        for (int kk = 0; kk < 3; kk++) {
            int k = q * 3 + kk;
            float dy = AO[(2 * k) * 128 + t]     + b_off[2 * k];
            float dx = AO[(2 * k + 1) * 128 + t] + b_off[2 * k + 1];
            float mm = AO[(18 + k) * 128 + t]    + b_mod[k];
            float mask = 2.0f / (1.0f + __expf(-mm));
            float py = dy + (float)hrow - 1.0f + (float)(k / 3);
            float px = dx + (float)t - 1.0f + (float)(k % 3);
            int idx = (b * 9 + k) * HWSZ + p;
            pyA[idx] = py;
            pxA[idx] = px;
            mA[idx] = mask;
        }
    }
}

// ---------------------------------------------------------------------------
// Kernel B2: bilinear sample + reduction GEMM with LDS-staged x window.
// Round-3 established B's wall: distinct-64B-lines through TA (~2.35 cy/line,
// 183 us) -- NCHW re-touches the same geometry once per channel. Fix: stage
// [16 rows][128 cols] per channel-PAIR as {chA,chB} float2 (16 KB, double-
// buffered 32 KB), taps via ds_read_b64. Staging lanes write consecutive
// float2s (strided-column map) -> conflict-free.
// Halves split K for sampling (k0-3/k5-8, k4 by half0) exchanging blended
// scalars via a 4.6KB LDS s-buf, and split OUTPUTS for the FMA (acc[32]).
// No break statements, no runtime-indexed arrays (round-5/6 scratch lesson);
// all weight bases via readfirstlane'd o0 -> s_load.
// Rare out-of-window taps (|dy|>7) re-gather from global (execz-skipped).
// ---------------------------------------------------------------------------
__global__ __launch_bounds__(512, 4) void sample_gemm_k(
    const float* __restrict__ x,
    const float* __restrict__ pyA, const float* __restrict__ pxA,
    const float* __restrict__ mA, const float* __restrict__ wt,
    const float* __restrict__ bias, float* __restrict__ out) {
    __shared__ float lds[12800];           // [0,8192) staging dbuf; [8192,12800) s-buf

    int b     = blockIdx.x & 7;
    int strip = blockIdx.x >> 3;           // 0..63 : 2-row strip
    int tid   = threadIdx.x;
    int t     = tid & 255;
    int half  = tid >> 8;
    int o0    = __builtin_amdgcn_readfirstlane((tid >> 8) << 5);  // SGPR
    int p     = strip * 256 + t;
    int h0    = strip * 2;
    int lo    = min(max(h0 - 7, 0), H_ - WIN_);   // staged rows [lo, lo+16)

    const float* xB = x + b * C_ * HWSZ;

    // ---- per-k sampling state: entries 0..3 = own k-group, entry 4 = k4 ----
    int kbase = half ? 5 : 0;
    float ca0[5], ca1[5], ca2[5], ca3[5];
    int   cpk[5];
#pragma unroll
    for (int i = 0; i < 5; i++) {          // constant trip, no break -> unrolls
        int k = (i < 4) ? (kbase + i) : 4;
        int idx = (b * 9 + k) * HWSZ + p;
        float py = pyA[idx], px = pxA[idx], m = mA[idx];

        float y0f = floorf(py), x0f = floorf(px);
        float wy = py - y0f, wx = px - x0f;
        int y0 = (int)y0f, x0 = (int)x0f;
        int y1 = y0 + 1;
        float vy0 = (y0 >= 0 && y0 < H_) ? 1.0f : 0.0f;
        float vy1 = (y1 >= 0 && y1 < H_) ? 1.0f : 0.0f;
        float vx0 = (x0 >= 0 && x0 < W_) ? 1.0f : 0.0f;
        float vx1 = (x0 >= -1 && x0 < W_ - 1) ? 1.0f : 0.0f;
        int y0c = min(max(y0, 0), H_ - 1), y1c = min(max(y1, 0), H_ - 1);

        float w00 = (1.0f - wy) * (1.0f - wx) * vy0 * vx0 * m;
        float w01 = (1.0f - wy) * wx * vy0 * vx1 * m;
        float w10 = wy * (1.0f - wx) * vy1 * vx0 * m;
        float w11 = wy * wx * vy1 * vx1 * m;

        int lc   = min(max(x0, 0), W_ - 2);      // cols lc, lc+1 staged & valid
        bool xlo = (x0 < 0);
        bool xhi = (x0 > W_ - 2);
        ca0[i] = xhi ? 0.0f : (xlo ? w01 : w00);
        ca1[i] = xlo ? 0.0f : (xhi ? w00 : w01);
        ca2[i] = xhi ? 0.0f : (xlo ? w11 : w10);
        ca3[i] = xlo ? 0.0f : (xhi ? w10 : w11);

        int r0c = min(max(y0c - lo, 0), WIN_ - 1);
        int r1c = min(max(y1c - lo, 0), WIN_ - 1);
        int in0 = (y0c >= lo && y0c < lo + WIN_) ? 1 : 0;
        int in1 = (y1c >= lo && y1c < lo + WIN_) ? 1 : 0;
        cpk[i] = lc | (r0c << 7) | (r1c << 11) | (in0 << 15) | (in1 << 16)
               | (y0c << 17) | (y1c << 24);
    }

    float acc[32];
#pragma unroll
    for (int o = 0; o < 32; o++) acc[o] = 0.0f;
    float2* sb = (float2*)(lds + 8192);

    // staging map: (row = tid>>5, 4 cols = (tid&31) + 32j) -> lanes write
    // consecutive float2s per j -> 2-way bank aliasing = free.
    int srow = tid >> 5;                   // 0..15
    int L    = tid & 31;

    {   // prologue: stage channel-pair 0 into buffer 0
        const float* s0 = xB + (lo + srow) * W_;
#pragma unroll
        for (int j = 0; j < 4; j++) {
            int col = L + 32 * j;
            ((float2*)lds)[srow * W_ + col] = make_float2(s0[col], s0[HWSZ + col]);
        }
    }
    __syncthreads();

    // one sampling step: literal array index I, runtime sb slot KIDX
#define SAMP(I, KIDX)                                                          \
    {                                                                          \
        int pk = cpk[I];                                                       \
        int lc_ = pk & 127;                                                    \
        int i0 = (((pk >> 7) & 15)) * W_ + lc_;                                \
        int i1 = (((pk >> 11) & 15)) * W_ + lc_;                               \
        float2 p00 = S[i0], p01 = S[i0 + 1];                                   \
        float2 p10 = S[i1], p11 = S[i1 + 1];                                   \
        if (__builtin_expect((pk & (1 << 15)) == 0, 0)) {                      \
            const float* xa = xc2 + ((pk >> 17) & 127) * W_ + lc_;             \
            f2u g0 = *(const f2u*)xa;                                          \
            f2u g1 = *(const f2u*)(xa + HWSZ);                                 \
            p00 = make_float2(g0.x, g1.x);                                     \
            p01 = make_float2(g0.y, g1.y);                                     \
        }                                                                      \
        if (__builtin_expect((pk & (1 << 16)) == 0, 0)) {                      \
            const float* xa = xc2 + ((pk >> 24) & 127) * W_ + lc_;             \
            f2u g0 = *(const f2u*)xa;                                          \
            f2u g1 = *(const f2u*)(xa + HWSZ);                                 \
            p10 = make_float2(g0.x, g1.x);                                     \
            p11 = make_float2(g0.y, g1.y);                                     \
        }                                                                      \
        float sA_ = ca0[I] * p00.x + ca1[I] * p01.x + ca2[I] * p10.x + ca3[I] * p11.x; \
        float sB_ = ca0[I] * p00.y + ca1[I] * p01.y + ca2[I] * p10.y + ca3[I] * p11.y; \
        sb[(KIDX) * 256 + t] = make_float2(sA_, sB_);                          \
    }

    for (int cp = 0; cp < 32; cp++) {
        float pga[4], pgb[4];
        if (cp < 31) {                     // prefetch next channel-pair
            const float* sn = xB + (2 * (cp + 1)) * HWSZ + (lo + srow) * W_;
#pragma unroll
            for (int j = 0; j < 4; j++) {
                int col = L + 32 * j;
                pga[j] = sn[col];
                pgb[j] = sn[HWSZ + col];
            }
        }
        const float2* S   = (const float2*)lds + (cp & 1) * 2048;
        const float*  xc2 = xB + 2 * cp * HWSZ;   // cold-path base (ch pair)

        SAMP(0, kbase + 0);
        SAMP(1, kbase + 1);
        SAMP(2, kbase + 2);
        SAMP(3, kbase + 3);
        if (!half) SAMP(4, 4);             // wave-uniform branch, no barrier

        if (cp < 31) {
            float2* d = (float2*)lds + ((cp + 1) & 1) * 2048;
#pragma unroll
            for (int j = 0; j < 4; j++)
                d[srow * W_ + L + 32 * j] = make_float2(pga[j], pgb[j]);
        }
        __syncthreads();                   // s-buf + next staging visible

        const float* wk = wt + (2 * cp) * O_ + o0;     // SGPR base -> s_load
#pragma unroll
        for (int k = 0; k < 9; k++) {
            float2 s = sb[k * 256 + t];
            const float* wA = wk + k * (C_ * O_);
            const float* wB = wA + O_;
#pragma unroll
            for (int o = 0; o < 32; o++) acc[o] += s.x * wA[o] + s.y * wB[o];
        }
        __syncthreads();                   // s-buf consumed before rewrite
    }
#undef SAMP

    // direct write-out: each half owns its 32 output planes
    int obase = (b * O_ + o0) * HWSZ + p;
#pragma unroll
    for (int o = 0; o < 32; o++)
        out[obase + o * HWSZ] = acc[o] + bias[o0 + o];
}

// ---------------------------------------------------------------------------
extern "C" void kernel_launch(void* const* d_in, const int* in_sizes, int n_in,
                              void* d_out, int out_size, void* d_ws, size_t ws_size,
                              hipStream_t stream) {
    const float* x     = (const float*)d_in[0];
    const float* w_off = (const float*)d_in[1];
    const float* b_off = (const float*)d_in[2];
    const float* w_mod = (const float*)d_in[3];
    const float* b_mod = (const float*)d_in[4];
    const float* w     = (const float*)d_in[5];
    const float* bias  = (const float*)d_in[6];
    float* out = (float*)d_out;

    const int nCoord = B_ * K2_ * HWSZ;   // 1,179,648
    float* pyA = (float*)d_ws;
    float* pxA = pyA + nCoord;
    float* mA  = pxA + nCoord;
    float* wt  = mA + nCoord;             // 36,864 floats
    float* wom = wt + K2_ * C_ * O_;      // 16,128 floats (C*28*9)

    const int nPrep = K2_ * C_ * O_ + C_ * 252;   // 52,992
    hipLaunchKernelGGL(prep_weights_k, dim3((nPrep + 255) / 256), dim3(256),
                       0, stream, w, w_off, w_mod, wt, wom);
    hipLaunchKernelGGL(conv_offmask_k, dim3(1024), dim3(512), 0, stream,
                       x, wom, b_off, b_mod, pyA, pxA, mA);
    hipLaunchKernelGGL(sample_gemm_k, dim3(512), dim3(512), 0, stream,
                       x, pyA, pxA, mA, wt, bias, out);
}

// Round 8
// 303.588 us; speedup vs baseline: 25.5132x; 1.5963x over previous
//
#include <hip/hip_runtime.h>
#include <math.h>

#define H_ 128
#define W_ 128
#define C_ 64
#define O_ 64
#define B_ 8
#define K2_ 9
#define HWSZ (H_*W_)

// 8-byte vector load with only 4-byte alignment guarantee (column-pair merge).
typedef float f2u __attribute__((ext_vector_type(2), aligned(4)));

// ---------------------------------------------------------------------------
// Kernel P: weight prep.
//  wt  (K2, C, O)  : sample-GEMM weights, contiguous in o -> clean s_load.
//  wom (C, 28, 9)  : offset(18)+mask(9) conv weights per channel, row 27 = 0
//                    (pad so 4 output-quarters run fixed 7-row loops).
// ---------------------------------------------------------------------------
__global__ __launch_bounds__(256) void prep_weights_k(
    const float* __restrict__ w, const float* __restrict__ w_off,
    const float* __restrict__ w_mod, float* __restrict__ wt,
    float* __restrict__ wom) {
    int id = blockIdx.x * 256 + threadIdx.x;
    if (id < K2_ * C_ * O_) {              // id = k*C*O + c*O + o
        int o = id & (O_ - 1);
        int c = (id >> 6) & (C_ - 1);
        int k = id / (C_ * O_);
        wt[id] = w[(o * C_ + c) * K2_ + k];
    }
    int id2 = id - K2_ * C_ * O_;
    if (id2 >= 0 && id2 < C_ * 252) {      // id2 = c*252 + tt*9 + k
        int k = id2 % 9;
        int tt = (id2 / 9) % 28;
        int c = id2 / 252;
        float v = 0.0f;
        if (tt < 18)      v = w_off[(tt * C_ + c) * K2_ + k];
        else if (tt < 27) v = w_mod[((tt - 18) * C_ + c) * K2_ + k];
        wom[id2] = v;
    }
}

// ---------------------------------------------------------------------------
// Kernel A3: offset/mask 3x3 conv, weight-stream-amortized.
// Rounds 1..7 lesson: A sat ~130us (floor 27) through TWO different tap
// paths; the invariant limiter is the per-c scalar weight chain (s_load
// latency not coverable by the few FMAs per weight, SGPRs too small to
// double-buffer). Fix: 2 PIXELS per thread (rows h0/h0+1 share a 4x3 tap
// stencil: 12 loads, each weight used twice -> 126 FMA per 63 weight floats)
// + o-quarter split (7 outs/quarter, wom row 27 = zero pad).
// No barriers in the c-loop; taps coalesced global, prefetched one c ahead;
// weight base readfirstlane'd -> s_load. Block 512 = 128 cols x 4 quarters,
// covers a 2-row strip (256 px). Grid 512 -> 2 blocks/CU, 16 waves.
// ---------------------------------------------------------------------------
__global__ __launch_bounds__(512, 4) void conv_offmask_k(
    const float* __restrict__ x,
    const float* __restrict__ wom, const float* __restrict__ b_off,
    const float* __restrict__ b_mod,
    float* __restrict__ pyA, float* __restrict__ pxA, float* __restrict__ mA) {
    __shared__ float AO[28 * 256];         // 28.7 KB: quarter-sum exchange

    int b     = blockIdx.x & 7;            // batch -> XCD (L2 locality)
    int strip = blockIdx.x >> 3;           // 0..63 : 2-row strip
    int tid   = threadIdx.x;
    int t     = tid & 127;                 // column
    int q     = tid >> 7;                  // 0..3 : output quarter
    int qu    = __builtin_amdgcn_readfirstlane(q);   // SGPR for weight base
    int h0    = strip * 2;

    // 12-tap shared stencil: rows h0-1..h0+2, cols t-1..t+1.
    // px0 (row h0) uses local rows 0..2; px1 (row h0+1) uses rows 1..3.
    int offs[12]; float valid[12];
#pragma unroll
    for (int r = 0; r < 4; r++) {
#pragma unroll
        for (int cx = 0; cx < 3; cx++) {
            int yy = h0 - 1 + r, xx = t - 1 + cx;
            bool vv = (yy >= 0 && yy < H_ && xx >= 0 && xx < W_);
            int yc = min(max(yy, 0), H_ - 1);
            int xc = min(max(xx, 0), W_ - 1);
            offs[r * 3 + cx] = yc * W_ + xc;
            valid[r * 3 + cx] = vv ? 1.0f : 0.0f;
        }
    }

    float acc0[7], acc1[7];
#pragma unroll
    for (int o = 0; o < 7; o++) { acc0[o] = 0.0f; acc1[o] = 0.0f; }

    const float* xb = x + b * C_ * HWSZ;

    // prefetch c=0 taps
    float v[12];
#pragma unroll
    for (int i = 0; i < 12; i++) v[i] = xb[offs[i]] * valid[i];

    for (int c = 0; c < C_; c++) {
        const float* xn = xb + min(c + 1, C_ - 1) * HWSZ;
        float vn[12];
#pragma unroll
        for (int i = 0; i < 12; i++) vn[i] = xn[offs[i]] * valid[i];

        const float* wq = wom + c * 252 + qu * 63;   // SGPR base -> s_load
#pragma unroll
        for (int o = 0; o < 7; o++) {
#pragma unroll
            for (int kk = 0; kk < 9; kk++) {
                float wv = wq[o * 9 + kk];
                int ki = kk / 3, kj = kk % 3;        // compile-time
                acc0[o] += v[ki * 3 + kj] * wv;      // px row h0
                acc1[o] += v[(ki + 1) * 3 + kj] * wv;// px row h0+1
            }
        }
#pragma unroll
        for (int i = 0; i < 12; i++) v[i] = vn[i];
    }

    // quarter sums -> LDS (rows 0..27; row 27 is the zero-pad output)
#pragma unroll
    for (int o = 0; o < 7; o++) {
        AO[(qu * 7 + o) * 256 + t]       = acc0[o];
        AO[(qu * 7 + o) * 256 + 128 + t] = acc1[o];
    }
    __syncthreads();

    // epilogue: 256 threads, 1 pixel each, all 9 k's -> coords out
    if (tid < 256) {
        int px = tid;                      // 0..127 row h0, 128..255 row h0+1
        int hh = h0 + (px >> 7);
        int ww = px & 127;
        int p  = hh * W_ + ww;
#pragma unroll
        for (int k = 0; k < 9; k++) {
            float dy = AO[(2 * k) * 256 + px]     + b_off[2 * k];
            float dx = AO[(2 * k + 1) * 256 + px] + b_off[2 * k + 1];
            float mm = AO[(18 + k) * 256 + px]    + b_mod[k];
            float mask = 2.0f / (1.0f + __expf(-mm));
            float py = dy + (float)hh - 1.0f + (float)(k / 3);
            float px_ = dx + (float)ww - 1.0f + (float)(k % 3);
            int idx = (b * 9 + k) * HWSZ + p;
            pyA[idx] = py;
            pxA[idx] = px_;
            mA[idx] = mask;
        }
    }
}

// ---------------------------------------------------------------------------
// Kernel B (round-3 version, verbatim): bilinear sample + reduction GEMM,
// column-pair merged dwordx2 gathers. Measured 183us = TA roofline for this
// divergence pattern (~47 cy/wave-gather). Three LDS-staging attempts
// (r2/r6/r7) all lost to it on VALU/addressing overhead -- do not revisit.
// ---------------------------------------------------------------------------
__global__ __launch_bounds__(512) void sample_gemm_k(
    const float* __restrict__ x,
    const float* __restrict__ pyA, const float* __restrict__ pxA,
    const float* __restrict__ mA, const float* __restrict__ wt,
    const float* __restrict__ bias, float* __restrict__ out) {
    __shared__ float red[O_ * 256];            // 64 KB

    int b     = blockIdx.x & 7;
    int strip = blockIdx.x >> 3;
    int tid   = threadIdx.x;
    int t     = tid & 255;
    int half  = tid >> 8;
    int c0    = __builtin_amdgcn_readfirstlane(half << 5);  // wave-uniform SGPR
    int p     = strip * 256 + t;

    float acc[O_];
#pragma unroll
    for (int o = 0; o < O_; o++) acc[o] = 0.0f;

    const float* xb = x + (b * C_ + c0) * HWSZ;

    for (int k = 0; k < 9; k++) {
        int idx = (b * 9 + k) * HWSZ + p;
        float py = pyA[idx];
        float px = pxA[idx];
        float m  = mA[idx];

        float y0f = floorf(py), x0f = floorf(px);
        float wy = py - y0f, wx = px - x0f;
        int y0 = (int)y0f, x0 = (int)x0f;
        int y1 = y0 + 1;
        float vy0 = (y0 >= 0 && y0 < H_) ? 1.0f : 0.0f;
        float vy1 = (y1 >= 0 && y1 < H_) ? 1.0f : 0.0f;
        float vx0 = (x0 >= 0 && x0 < W_) ? 1.0f : 0.0f;
        float vx1 = (x0 >= -1 && x0 < W_ - 1) ? 1.0f : 0.0f;
        int y0c = min(max(y0, 0), H_ - 1), y1c = min(max(y1, 0), H_ - 1);

        float w00 = (1.0f - wy) * (1.0f - wx) * vy0 * vx0 * m;
        float w01 = (1.0f - wy) * wx * vy0 * vx1 * m;
        float w10 = wy * (1.0f - wx) * vy1 * vx0 * m;
        float w11 = wy * wx * vy1 * vx1 * m;

        // column-pair merge: one 8B load per row covers both x-taps.
        int lc   = min(max(x0, 0), W_ - 2);    // 0..126, load [lc, lc+1]
        bool xlo = (x0 < 0);                   // v01 lives at f.x
        bool xhi = (x0 > W_ - 2);              // v00 lives at f.y
        float a00 = xhi ? 0.0f : (xlo ? w01 : w00);
        float a01 = xlo ? 0.0f : (xhi ? w00 : w01);
        float a10 = xhi ? 0.0f : (xlo ? w11 : w10);
        float a11 = xlo ? 0.0f : (xhi ? w10 : w11);

        int r0 = y0c * W_ + lc;
        int r1 = y1c * W_ + lc;

        const float* wp = wt + k * (C_ * O_) + c0 * O_;   // uniform -> s_load
        for (int c = 0; c < 32; c++) {
            const float* xc = xb + c * HWSZ;
            f2u f0 = *(const f2u*)(xc + r0);
            f2u f1 = *(const f2u*)(xc + r1);
            float s = a00 * f0.x + a01 * f0.y + a10 * f1.x + a11 * f1.y;
            const float* wpc = wp + c * O_;
#pragma unroll
            for (int o = 0; o < O_; o++) acc[o] += s * wpc[o];
        }
    }

    if (half) {
#pragma unroll
        for (int o = 0; o < O_; o++) red[o * 256 + t] = acc[o];  // stride-1
    }
    __syncthreads();
    if (!half) {
        int obase = b * O_ * HWSZ + p;
#pragma unroll
        for (int o = 0; o < O_; o++)
            out[obase + o * HWSZ] = acc[o] + red[o * 256 + t] + bias[o];
    }
}

// ---------------------------------------------------------------------------
extern "C" void kernel_launch(void* const* d_in, const int* in_sizes, int n_in,
                              void* d_out, int out_size, void* d_ws, size_t ws_size,
                              hipStream_t stream) {
    const float* x     = (const float*)d_in[0];
    const float* w_off = (const float*)d_in[1];
    const float* b_off = (const float*)d_in[2];
    const float* w_mod = (const float*)d_in[3];
    const float* b_mod = (const float*)d_in[4];
    const float* w     = (const float*)d_in[5];
    const float* bias  = (const float*)d_in[6];
    float* out = (float*)d_out;

    const int nCoord = B_ * K2_ * HWSZ;   // 1,179,648
    float* pyA = (float*)d_ws;
    float* pxA = pyA + nCoord;
    float* mA  = pxA + nCoord;
    float* wt  = mA + nCoord;             // 36,864 floats
    float* wom = wt + K2_ * C_ * O_;      // 16,128 floats (C*28*9)

    const int nPrep = K2_ * C_ * O_ + C_ * 252;   // 52,992
    hipLaunchKernelGGL(prep_weights_k, dim3((nPrep + 255) / 256), dim3(256),
                       0, stream, w, w_off, w_mod, wt, wom);
    hipLaunchKernelGGL(conv_offmask_k, dim3(512), dim3(512), 0, stream,
                       x, wom, b_off, b_mod, pyA, pxA, mA);
    hipLaunchKernelGGL(sample_gemm_k, dim3(512), dim3(512), 0, stream,
                       x, pyA, pxA, mA, wt, bias, out);
}

// Round 9
// 297.328 us; speedup vs baseline: 26.0503x; 1.0211x over previous
//
#include <hip/hip_runtime.h>
#include <math.h>

#define H_ 128
#define W_ 128
#define C_ 64
#define O_ 64
#define B_ 8
#define K2_ 9
#define HWSZ (H_*W_)

// vector global loads with only 4-byte alignment guarantee (gfx950 supports
// unaligned global access; r3's f2u precedent emitted dwordx2 fine).
typedef float f2u __attribute__((ext_vector_type(2), aligned(4)));
typedef float f4u __attribute__((ext_vector_type(4), aligned(4)));

// ---------------------------------------------------------------------------
// Kernel P: weight prep.
//  wt  (K2, C, O)  : sample-GEMM weights, contiguous in o -> clean s_load.
//  wom (C, 28, 9)  : offset(18)+mask(9) conv weights per channel, row 27 = 0
//                    (pad so 4 output-quarters run fixed 7-row loops).
// ---------------------------------------------------------------------------
__global__ __launch_bounds__(256) void prep_weights_k(
    const float* __restrict__ w, const float* __restrict__ w_off,
    const float* __restrict__ w_mod, float* __restrict__ wt,
    float* __restrict__ wom) {
    int id = blockIdx.x * 256 + threadIdx.x;
    if (id < K2_ * C_ * O_) {              // id = k*C*O + c*O + o
        int o = id & (O_ - 1);
        int c = (id >> 6) & (C_ - 1);
        int k = id / (C_ * O_);
        wt[id] = w[(o * C_ + c) * K2_ + k];
    }
    int id2 = id - K2_ * C_ * O_;
    if (id2 >= 0 && id2 < C_ * 252) {      // id2 = c*252 + tt*9 + k
        int k = id2 % 9;
        int tt = (id2 / 9) % 28;
        int c = id2 / 252;
        float v = 0.0f;
        if (tt < 18)      v = w_off[(tt * C_ + c) * K2_ + k];
        else if (tt < 27) v = w_mod[((tt - 18) * C_ + c) * K2_ + k];
        wom[id2] = v;
    }
}

// ---------------------------------------------------------------------------
// Kernel A4: offset/mask 3x3 conv, TA-instruction-minimized.
// r8 lesson: weight-stream amortization moved A only 10% -- A is bound by
// the same wall B had (r3): TA cost ~ 2.35cy x distinct-lines PER LOAD
// INSTRUCTION. A3 issued 12 scalar tap loads/thread/c (and duplicated them
// across 4 o-quarters): ~66us of TA. Fix: 2x2 pixel quad per thread ->
// stencil = 4 rows x 4 cols = FOUR dwordx4 loads per channel; channels
// split across thread-halves. Per CU per c: 64 load-instrs (~640 lines)
// -> ~20us TA, under the ~30us FMA floor.
// Column-edge remap (u==0 / u==63) folded into compile-time-indexed
// cndmask selects (no runtime vector indexing -> no scratch).
// Weight base readfirstlane'd -> s_load. acc[7][4] = 28 VGPRs.
// Block 512 = 64 col-pairs x 4 o-quarters x 2 c-halves; 2-row strip.
// Grid 512 -> 2 blocks/CU, 16 waves.
// ---------------------------------------------------------------------------
__global__ __launch_bounds__(512, 4) void conv_offmask_k(
    const float* __restrict__ x,
    const float* __restrict__ wom, const float* __restrict__ b_off,
    const float* __restrict__ b_mod,
    float* __restrict__ pyA, float* __restrict__ pxA, float* __restrict__ mA) {
    __shared__ float AO[28 * 256];         // 28.7 KB: out-row exchange

    int b     = blockIdx.x & 7;            // batch -> XCD (L2 locality)
    int strip = blockIdx.x >> 3;           // 0..63 : 2-row strip
    int tid   = threadIdx.x;
    int u     = tid & 63;                  // col-pair: cols 2u, 2u+1
    int oq    = (tid >> 6) & 3;            // output quarter (wave-uniform)
    int chh   = tid >> 8;                  // c-half (wave-uniform)
    int qu    = __builtin_amdgcn_readfirstlane(oq);
    int hu    = __builtin_amdgcn_readfirstlane(chh);
    int h0    = strip * 2;

    // stencil rows h0-1 .. h0+2 (clamped addr + validity)
    int   yc[4]; float vval[4];
#pragma unroll
    for (int r = 0; r < 4; r++) {
        int yy = h0 - 1 + r;
        vval[r] = (yy >= 0 && yy < H_) ? 1.0f : 0.0f;
        yc[r] = min(max(yy, 0), H_ - 1);
    }
    // stencil cols 2u-1 .. 2u+2 via one dwordx4 at lc (edge lanes shifted)
    int  lc  = min(max(2 * u - 1, 0), W_ - 4);
    bool u0  = (u == 0);
    bool u63 = (u == 63);

    const float* xb = x + (b * C_ + hu * 32) * HWSZ;   // SGPR base

    float acc[7][4];
#pragma unroll
    for (int o = 0; o < 7; o++)
#pragma unroll
        for (int j = 0; j < 4; j++) acc[o][j] = 0.0f;

    f4u L[4];
#pragma unroll
    for (int r = 0; r < 4; r++)
        L[r] = *(const f4u*)(xb + yc[r] * W_ + lc);

    for (int c = 0; c < 32; c++) {
        // prefetch next channel's 4 row-vectors
        const float* xn = xb + min(c + 1, 31) * HWSZ;
        f4u Ln[4];
#pragma unroll
        for (int r = 0; r < 4; r++)
            Ln[r] = *(const f4u*)(xn + yc[r] * W_ + lc);

        // build taps v[r][j] = x[row h0-1+r][col 2u-1+j] (0 outside image)
        float v[4][4];
#pragma unroll
        for (int r = 0; r < 4; r++) {
            float l0 = L[r].x, l1 = L[r].y, l2 = L[r].z, l3 = L[r].w;
            v[r][0] = (u0 ? 0.0f : (u63 ? l1 : l0)) * vval[r];
            v[r][1] = (u0 ? l0   : (u63 ? l2 : l1)) * vval[r];
            v[r][2] = (u0 ? l1   : (u63 ? l3 : l2)) * vval[r];
            v[r][3] = (u0 ? l2   : (u63 ? 0.0f : l3)) * vval[r];
        }

        const float* wq = wom + (hu * 32 + c) * 252 + qu * 63;  // s_load
#pragma unroll
        for (int o = 0; o < 7; o++) {
#pragma unroll
            for (int kk = 0; kk < 9; kk++) {
                float wv = wq[o * 9 + kk];
                int ki = kk / 3, kj = kk % 3;          // compile-time
                acc[o][0] += v[ki][kj]     * wv;       // (h0,   2u)
                acc[o][1] += v[ki][kj + 1] * wv;       // (h0,   2u+1)
                acc[o][2] += v[ki + 1][kj]     * wv;   // (h0+1, 2u)
                acc[o][3] += v[ki + 1][kj + 1] * wv;   // (h0+1, 2u+1)
            }
        }
#pragma unroll
        for (int r = 0; r < 4; r++) L[r] = Ln[r];
    }

    // exchange: c-half 1 writes, c-half 0 adds -> AO complete
    float2* AO2 = (float2*)AO;
    if (chh == 1) {
#pragma unroll
        for (int o = 0; o < 7; o++) {
            AO2[(qu * 7 + o) * 128 + u]      = make_float2(acc[o][0], acc[o][1]);
            AO2[(qu * 7 + o) * 128 + 64 + u] = make_float2(acc[o][2], acc[o][3]);
        }
    }
    __syncthreads();
    if (chh == 0) {
#pragma unroll
        for (int o = 0; o < 7; o++) {
            int i0 = (qu * 7 + o) * 128 + u;
            float2 t0 = AO2[i0], t1 = AO2[i0 + 64];
            t0.x += acc[o][0]; t0.y += acc[o][1];
            t1.x += acc[o][2]; t1.y += acc[o][3];
            AO2[i0] = t0; AO2[i0 + 64] = t1;
        }
    }
    __syncthreads();

    // epilogue: 256 threads, 1 pixel each, all 9 k's -> coords out
    if (tid < 256) {
        int px = tid;                      // 0..127 row h0, 128..255 row h0+1
        int hh = h0 + (px >> 7);
        int ww = px & 127;
        int p  = hh * W_ + ww;
#pragma unroll
        for (int k = 0; k < 9; k++) {
            float dy = AO[(2 * k) * 256 + px]     + b_off[2 * k];
            float dx = AO[(2 * k + 1) * 256 + px] + b_off[2 * k + 1];
            float mm = AO[(18 + k) * 256 + px]    + b_mod[k];
            float mask = 2.0f / (1.0f + __expf(-mm));
            float py = dy + (float)hh - 1.0f + (float)(k / 3);
            float px_ = dx + (float)ww - 1.0f + (float)(k % 3);
            int idx = (b * 9 + k) * HWSZ + p;
            pyA[idx] = py;
            pxA[idx] = px_;
            mA[idx] = mask;
        }
    }
}

// ---------------------------------------------------------------------------
// Kernel B (round-3 version, verbatim): bilinear sample + reduction GEMM,
// column-pair merged dwordx2 gathers. Measured 180us = TA roofline for this
// divergence pattern (~47 cy/wave-gather). Three LDS-staging attempts
// (r2/r6/r7) all lost to it on VALU/addressing overhead -- do not revisit.
// ---------------------------------------------------------------------------
__global__ __launch_bounds__(512) void sample_gemm_k(
    const float* __restrict__ x,
    const float* __restrict__ pyA, const float* __restrict__ pxA,
    const float* __restrict__ mA, const float* __restrict__ wt,
    const float* __restrict__ bias, float* __restrict__ out) {
    __shared__ float red[O_ * 256];            // 64 KB

    int b     = blockIdx.x & 7;
    int strip = blockIdx.x >> 3;
    int tid   = threadIdx.x;
    int t     = tid & 255;
    int half  = tid >> 8;
    int c0    = __builtin_amdgcn_readfirstlane(half << 5);  // wave-uniform SGPR
    int p     = strip * 256 + t;

    float acc[O_];
#pragma unroll
    for (int o = 0; o < O_; o++) acc[o] = 0.0f;

    const float* xb = x + (b * C_ + c0) * HWSZ;

    for (int k = 0; k < 9; k++) {
        int idx = (b * 9 + k) * HWSZ + p;
        float py = pyA[idx];
        float px = pxA[idx];
        float m  = mA[idx];

        float y0f = floorf(py), x0f = floorf(px);
        float wy = py - y0f, wx = px - x0f;
        int y0 = (int)y0f, x0 = (int)x0f;
        int y1 = y0 + 1;
        float vy0 = (y0 >= 0 && y0 < H_) ? 1.0f : 0.0f;
        float vy1 = (y1 >= 0 && y1 < H_) ? 1.0f : 0.0f;
        float vx0 = (x0 >= 0 && x0 < W_) ? 1.0f : 0.0f;
        float vx1 = (x0 >= -1 && x0 < W_ - 1) ? 1.0f : 0.0f;
        int y0c = min(max(y0, 0), H_ - 1), y1c = min(max(y1, 0), H_ - 1);

        float w00 = (1.0f - wy) * (1.0f - wx) * vy0 * vx0 * m;
        float w01 = (1.0f - wy) * wx * vy0 * vx1 * m;
        float w10 = wy * (1.0f - wx) * vy1 * vx0 * m;
        float w11 = wy * wx * vy1 * vx1 * m;

        // column-pair merge: one 8B load per row covers both x-taps.
        int lc   = min(max(x0, 0), W_ - 2);    // 0..126, load [lc, lc+1]
        bool xlo = (x0 < 0);                   // v01 lives at f.x
        bool xhi = (x0 > W_ - 2);              // v00 lives at f.y
        float a00 = xhi ? 0.0f : (xlo ? w01 : w00);
        float a01 = xlo ? 0.0f : (xhi ? w00 : w01);
        float a10 = xhi ? 0.0f : (xlo ? w11 : w10);
        float a11 = xlo ? 0.0f : (xhi ? w10 : w11);

        int r0 = y0c * W_ + lc;
        int r1 = y1c * W_ + lc;

        const float* wp = wt + k * (C_ * O_) + c0 * O_;   // uniform -> s_load
        for (int c = 0; c < 32; c++) {
            const float* xc = xb + c * HWSZ;
            f2u f0 = *(const f2u*)(xc + r0);
            f2u f1 = *(const f2u*)(xc + r1);
            float s = a00 * f0.x + a01 * f0.y + a10 * f1.x + a11 * f1.y;
            const float* wpc = wp + c * O_;
#pragma unroll
            for (int o = 0; o < O_; o++) acc[o] += s * wpc[o];
        }
    }

    if (half) {
#pragma unroll
        for (int o = 0; o < O_; o++) red[o * 256 + t] = acc[o];  // stride-1
    }
    __syncthreads();
    if (!half) {
        int obase = b * O_ * HWSZ + p;
#pragma unroll
        for (int o = 0; o < O_; o++)
            out[obase + o * HWSZ] = acc[o] + red[o * 256 + t] + bias[o];
    }
}

// ---------------------------------------------------------------------------
extern "C" void kernel_launch(void* const* d_in, const int* in_sizes, int n_in,
                              void* d_out, int out_size, void* d_ws, size_t ws_size,
                              hipStream_t stream) {
    const float* x     = (const float*)d_in[0];
    const float* w_off = (const float*)d_in[1];
    const float* b_off = (const float*)d_in[2];
    const float* w_mod = (const float*)d_in[3];
    const float* b_mod = (const float*)d_in[4];
    const float* w     = (const float*)d_in[5];
    const float* bias  = (const float*)d_in[6];
    float* out = (float*)d_out;

    const int nCoord = B_ * K2_ * HWSZ;   // 1,179,648
    float* pyA = (float*)d_ws;
    float* pxA = pyA + nCoord;
    float* mA  = pxA + nCoord;
    float* wt  = mA + nCoord;             // 36,864 floats
    float* wom = wt + K2_ * C_ * O_;      // 16,128 floats (C*28*9)

    const int nPrep = K2_ * C_ * O_ + C_ * 252;   // 52,992
    hipLaunchKernelGGL(prep_weights_k, dim3((nPrep + 255) / 256), dim3(256),
                       0, stream, w, w_off, w_mod, wt, wom);
    hipLaunchKernelGGL(conv_offmask_k, dim3(512), dim3(512), 0, stream,
                       x, wom, b_off, b_mod, pyA, pxA, mA);
    hipLaunchKernelGGL(sample_gemm_k, dim3(512), dim3(512), 0, stream,
                       x, pyA, pxA, mA, wt, bias, out);
}